// Round 1
// baseline (307.103 us; speedup 1.0000x reference)
//
#include <hip/hip_runtime.h>
#include <stdint.h>

// Problem constants
#define B_   8
#define C_   256
#define N_   2304          // 48*48 spatial
#define HID  128
#define O3   384           // 3*HID
#define NH   4
#define SCALE 0.0625f      // 256^-0.5
#define QPRE 0.09016844f   // SCALE * log2(e): q pre-scale so p = exp2(q.k)

typedef unsigned short u16;
typedef short  bf8  __attribute__((ext_vector_type(8)));   // 8 bf16 (4 VGPRs) MFMA A/B frag
typedef float  f4   __attribute__((ext_vector_type(4)));   // MFMA C/D frag
typedef u16    u16x8 __attribute__((ext_vector_type(8)));

#define MFMA(a,b,c) __builtin_amdgcn_mfma_f32_16x16x32_bf16((a),(b),(c),0,0,0)

static __device__ __forceinline__ u16 f2bf(float f){
    union { float f; unsigned int i; } v; v.f = f;
    unsigned int r = v.i + 0x7FFFu + ((v.i >> 16) & 1u);   // round-to-nearest-even
    return (u16)(r >> 16);
}
static __device__ __forceinline__ float fexp2(float x){
#if __has_builtin(__builtin_amdgcn_exp2f)
    return __builtin_amdgcn_exp2f(x);
#else
    return __expf(x * 0.69314718f);
#endif
}
static __device__ __forceinline__ u16 hi16(float f){       // truncating f32->bf16
    union { float f; unsigned int i; } v; v.f = f;
    return (u16)(v.i >> 16);
}
// async global->LDS DMA, 16B per lane; both sides contiguous per lane.
static __device__ __forceinline__ void dma16(const void* g, void* l){
    __builtin_amdgcn_global_load_lds(
        (const __attribute__((address_space(1))) void*)g,
        (__attribute__((address_space(3))) void*)l, 16, 0, 0);
}

// ---------------------------------------------------------------------------
// K0a: convert embed weights fp32 -> bf16.
__global__ __launch_bounds__(256) void k_wcvt(const float* __restrict__ w0,
                                              const float* __restrict__ w1,
                                              u16* __restrict__ Wbf){
    int s = blockIdx.y;
    const float* w = s ? w1 : w0;
    u16* o = Wbf + (size_t)s * (O3 * C_);
    int idx = (blockIdx.x * 256 + threadIdx.x) * 4;
    float4 v = *reinterpret_cast<const float4*>(&w[idx]);
    o[idx+0] = f2bf(v.x); o[idx+1] = f2bf(v.y);
    o[idx+2] = f2bf(v.z); o[idx+3] = f2bf(v.w);
}

// K0b: w_eff^T[s][oc][hc] = sum_head out_w_s[head*HID+hc][oc]  (heads identical)
__global__ __launch_bounds__(256) void k_weff(const float* __restrict__ w0,
                                              const float* __restrict__ w1,
                                              u16* __restrict__ weff){
    int gid = blockIdx.x * 256 + threadIdx.x;   // 2*128*256 = 65536
    int oc = gid & 255, hc = (gid >> 8) & 127, s = gid >> 15;
    const float* w = s ? w1 : w0;
    float acc = 0.f;
    #pragma unroll
    for (int h = 0; h < NH; ++h) acc += w[(h*HID + hc)*C_ + oc];
    weff[(s*C_ + oc)*HID + hc] = f2bf(acc);
}

// ---------------------------------------------------------------------------
// K1a: transpose+convert X[bs][c][n] fp32 -> Xt[bs][n][c] bf16 (Xt in d_out)
__global__ __launch_bounds__(256) void k_transpose(const float* __restrict__ x0,
                                                   const float* __restrict__ x1,
                                                   u16* __restrict__ Xt){
    __shared__ __align__(16) u16 tile[64][72];
    int z = blockIdx.z, b = z >> 1, s = z & 1;
    const float* X = (s ? x1 : x0) + (size_t)b * (C_ * N_);
    u16* out = Xt + (size_t)z * (N_ * C_);
    int n0 = blockIdx.x * 64, c0 = blockIdx.y * 64;
    int t = threadIdx.x;
    int lr = t >> 4, lc = (t & 15) * 4;
    #pragma unroll
    for (int rep = 0; rep < 4; ++rep){
        int c = lr + rep * 16;
        float4 v = *reinterpret_cast<const float4*>(&X[(size_t)(c0 + c) * N_ + n0 + lc]);
        tile[c][lc+0] = f2bf(v.x); tile[c][lc+1] = f2bf(v.y);
        tile[c][lc+2] = f2bf(v.z); tile[c][lc+3] = f2bf(v.w);
    }
    __syncthreads();
    int row = t >> 3, col8 = (t & 7) * 8;
    #pragma unroll
    for (int rep = 0; rep < 2; ++rep){
        int n = row + rep * 32;
        u16x8 v;
        #pragma unroll
        for (int j = 0; j < 8; ++j) v[j] = tile[col8 + j][n];
        *reinterpret_cast<u16x8*>(&out[(size_t)(n0 + n) * C_ + c0 + col8]) = v;
    }
}

// ---------------------------------------------------------------------------
// K1b: embed GEMM.  Q pre-scaled by QPRE.  K/V written in DMA-friendly
// chunk-interleaved layouts:
//   Kc[z][nc][cc][n&63][8] : elem (n,h) at ((n>>6)*16 + (h>>3))*512 + (n&63)*8 + (h&7)
//   Vc[z][nc][pc][hc][8]   : elem (hc,n) at ((n>>6)*8 + ((n>>3)&7))*1024 + hc*8 + (n&7)
__global__ __launch_bounds__(256, 4) void k_embed(const u16* __restrict__ Xt,
        const u16* __restrict__ Wbf,
        const float* __restrict__ b0, const float* __restrict__ b1,
        u16* __restrict__ Qt, u16* __restrict__ Kc, u16* __restrict__ Vc){
    int z = blockIdx.z, s = z & 1;
    const u16* W = Wbf + (size_t)s * (O3 * C_);
    const float* bias = s ? b1 : b0;
    const u16* Xb = Xt + (size_t)z * (N_ * C_);
    int lane = threadIdx.x & 63, wave = threadIdx.x >> 6;
    int l16 = lane & 15, quad = lane >> 4;
    int o0 = blockIdx.y * 64 + wave * 16;
    int n0 = blockIdx.x * 64;
    f4 acc[4] = {f4{0,0,0,0}, f4{0,0,0,0}, f4{0,0,0,0}, f4{0,0,0,0}};
    #pragma unroll
    for (int kk = 0; kk < 8; ++kk){           // K = 256 = 8 * 32
        bf8 a = *reinterpret_cast<const bf8*>(&W[(o0 + l16) * C_ + kk*32 + quad*8]);
        #pragma unroll
        for (int nt = 0; nt < 4; ++nt){
            bf8 bb = *reinterpret_cast<const bf8*>(&Xb[(size_t)(n0 + nt*16 + l16) * C_ + kk*32 + quad*8]);
            acc[nt] = MFMA(a, bb, acc[nt]);
        }
    }
    size_t zq = (size_t)z * (N_ * HID);
    #pragma unroll
    for (int nt = 0; nt < 4; ++nt){
        int n = n0 + nt*16 + l16;
        #pragma unroll
        for (int r = 0; r < 4; ++r){
            int o = o0 + quad*4 + r;
            float e = acc[nt][r] + bias[o];
            if (o < HID){
                Qt[zq + (size_t)n*HID + o] = f2bf(e * QPRE);
            } else if (o < 2*HID){
                int h = o - HID;
                Kc[zq + ((n>>6)*16 + (h>>3))*512 + ((n&63)<<3) + (h&7)] = f2bf(e);
            } else {
                int hc = o - 2*HID;
                Vc[zq + ((n>>6)*8 + ((n>>3)&7))*1024 + (hc<<3) + (n&7)] = f2bf(e);
            }
        }
    }
}

// ---------------------------------------------------------------------------
// K2 (fused): max-free flash attention + output projection + residual.
//   v2: waves split 64 rows x 64 keys as (2 row-halves x 2 key-halves) so each
//   K/V fragment read from LDS feeds 2 MFMAs (per-FLOP LDS traffic halved), and
//   K/V double-buffered: chunk nc+1 DMA issued before chunk-nc compute, single
//   __syncthreads per chunk (its vmcnt(0) drain lands on already-arrived loads).
//   Key-partial O/rowsum reduced across wave pairs via LDS in the epilogue.
__global__ __launch_bounds__(256, 2) void k_attn_out(const u16* __restrict__ Qt,
        const u16* __restrict__ Kc, const u16* __restrict__ Vc,
        const u16* __restrict__ weff,
        const float* __restrict__ ob0, const float* __restrict__ ob1,
        const float* __restrict__ x0, const float* __restrict__ x1,
        float* __restrict__ out){
    // LDS map (bytes):
    //   [0, 65536)      : K/V double buffer; buf b at b*32768: K 16 KB then V 16 KB
    //   [65536, 76288)  : P tiles, per wave 32 x 42 u16 (pad 42 -> conflict-free)
    // epilogue reuse of [0, 65536):
    //   [0, 33792)      : partial O, 64 x 132 f32
    //   [34816, 52224)  : H tile, 64 x 136 u16
    //   [53248, 53504)  : partial rowsum, 64 f32
    __shared__ __align__(16) u16 lds[38144];           // 76288 B -> 2 blocks/CU
    int bx = blockIdx.x;                      // 576 = 8 XCD * 72
    int xcd = bx & 7, t = bx >> 3;
    int z  = xcd*2 + (t >= 36 ? 1 : 0);       // XCD x serves z in {2x,2x+1}
    int mt = (t >= 36) ? (t - 36) : t;
    int b = z >> 1, s = z & 1;
    const u16* Q = Qt + (size_t)(b*2 + (1 - s)) * (N_ * HID);
    const u16* K = Kc + (size_t)(b*2 + s)       * (N_ * HID);
    const u16* V = Vc + (size_t)(b*2 + s)       * (N_ * HID);
    const u16* Wf   = weff + (size_t)s * (C_ * HID);
    const float* bias = s ? ob1 : ob0;
    const float* X = (s ? x1 : x0) + (size_t)b * (C_ * N_);
    float* O = out + (size_t)s * ((size_t)B_ * C_ * N_) + (size_t)b * (C_ * N_);
    int lane = threadIdx.x & 63, wave = threadIdx.x >> 6;
    int l16 = lane & 15, quad = lane >> 4;
    int rw = wave & 1, kw = wave >> 1;        // row-half, key-half
    int m0 = mt * 64 + rw * 32;

    // Q fragments for this wave's 32 rows: 2 row-tiles x 4 k-slices
    bf8 aq[2][4];
    #pragma unroll
    for (int rt = 0; rt < 2; ++rt)
        #pragma unroll
        for (int kk = 0; kk < 4; ++kk)
            aq[rt][kk] = *reinterpret_cast<const bf8*>(
                &Q[(size_t)(m0 + rt*16 + l16)*HID + kk*32 + quad*8]);

    bf8 ones;
    #pragma unroll
    for (int j = 0; j < 8; ++j) ones[j] = (short)0x3F80;   // bf16 1.0

    f4 oacc[2][8];
    #pragma unroll
    for (int rt = 0; rt < 2; ++rt)
        #pragma unroll
        for (int ct = 0; ct < 8; ++ct) oacc[rt][ct] = f4{0,0,0,0};
    f4 sumacc[2] = {f4{0,0,0,0}, f4{0,0,0,0}};

    u16* pw = lds + 32768 + wave * (32*42);
    const char* Kb = (const char*)K;
    const char* Vb = (const char*)V;

    // prologue: stage chunk 0 into buffer 0
    #pragma unroll
    for (int j = 0; j < 4; ++j){
        int ik = wave*4 + j;
        dma16(Kb + ((size_t)ik*512 + lane*8)*2, &lds[ik*512]);
    }
    #pragma unroll
    for (int j = 0; j < 4; ++j){
        int iv = wave*4 + j;
        dma16(Vb + ((size_t)(iv>>1)*1024 + (iv&1)*512 + lane*8)*2, &lds[8192 + iv*512]);
    }

    for (int nc = 0; nc < N_/64; ++nc){
        int cur = nc & 1;
        // drains vmcnt(0): chunk-nc DMA (overlapped previous compute) is in LDS;
        // also guarantees all waves done reading buf[cur^1] before we overwrite it.
        __syncthreads();
        if (nc < N_/64 - 1){                  // prefetch chunk nc+1 into other buffer
            u16* kb = lds + (cur^1)*16384;
            u16* vb = kb + 8192;
            #pragma unroll
            for (int j = 0; j < 4; ++j){
                int ik = wave*4 + j;
                dma16(Kb + ((size_t)((nc+1)*16 + ik)*512 + lane*8)*2, &kb[ik*512]);
            }
            #pragma unroll
            for (int j = 0; j < 4; ++j){
                int iv = wave*4 + j;
                dma16(Vb + ((size_t)((nc+1)*8 + (iv>>1))*1024 + (iv&1)*512 + lane*8)*2,
                      &vb[iv*512]);
            }
        }
        __builtin_amdgcn_sched_barrier(0);    // keep prefetch issued before compute
        const u16* kb = lds + cur*16384;
        const u16* vb = kb + 8192;
        // QK: this wave's S quarter = rows [m0,m0+32) x keys [kw*32, kw*32+32)
        f4 sacc[2][2] = {{f4{0,0,0,0}, f4{0,0,0,0}}, {f4{0,0,0,0}, f4{0,0,0,0}}};
        __builtin_amdgcn_s_setprio(1);
        #pragma unroll
        for (int kk = 0; kk < 4; ++kk)
            #pragma unroll
            for (int kt = 0; kt < 2; ++kt){
                bf8 bk = *reinterpret_cast<const bf8*>(
                    &kb[((kk*4+quad)*64 + kw*32 + kt*16 + l16)*8]);
                sacc[0][kt] = MFMA(aq[0][kk], bk, sacc[0][kt]);   // 1 read -> 2 MFMA
                sacc[1][kt] = MFMA(aq[1][kk], bk, sacc[1][kt]);
            }
        __builtin_amdgcn_s_setprio(0);
        // p = exp2(s), truncating bf16 store to per-wave P tile
        #pragma unroll
        for (int rt = 0; rt < 2; ++rt)
            #pragma unroll
            for (int kt = 0; kt < 2; ++kt)
                #pragma unroll
                for (int r = 0; r < 4; ++r)
                    pw[(rt*16 + quad*4 + r)*42 + kt*16 + l16] = hi16(fexp2(sacc[rt][kt][r]));
        // PV + rowsum over this wave's 32-key half (K-dim = 32 -> single MFMA step)
        bf8 ap[2];
        #pragma unroll
        for (int rt = 0; rt < 2; ++rt)
            ap[rt] = *reinterpret_cast<const bf8*>(&pw[(rt*16 + l16)*42 + quad*8]);
        __builtin_amdgcn_s_setprio(1);
        sumacc[0] = MFMA(ap[0], ones, sumacc[0]);
        sumacc[1] = MFMA(ap[1], ones, sumacc[1]);
        #pragma unroll
        for (int ct = 0; ct < 8; ++ct){
            bf8 bv = *reinterpret_cast<const bf8*>(
                &vb[((kw*4+quad)*128 + ct*16 + l16)*8]);
            oacc[0][ct] = MFMA(ap[0], bv, oacc[0][ct]);           // 1 read -> 2 MFMA
            oacc[1][ct] = MFMA(ap[1], bv, oacc[1][ct]);
        }
        __builtin_amdgcn_s_setprio(0);
    }

    // ---- epilogue: reduce key-halves, normalize, out-GEMM -------------------
    __syncthreads();                           // no DMA in flight (last chunk had none)
    float* fpo = (float*)lds;                  // 64 x 132 f32 partial O
    u16*  Hm   = lds + 17408;                  // byte 34816: 64 x 136 u16 H tile
    float* fps = (float*)((char*)lds + 53248); // 64 f32 partial rowsum
    if (kw == 1){
        #pragma unroll
        for (int rt = 0; rt < 2; ++rt){
            #pragma unroll
            for (int ct = 0; ct < 8; ++ct)
                #pragma unroll
                for (int r = 0; r < 4; ++r)
                    fpo[(rw*32 + rt*16 + quad*4 + r)*132 + ct*16 + l16] = oacc[rt][ct][r];
            if (l16 == 0)
                #pragma unroll
                for (int r = 0; r < 4; ++r)
                    fps[rw*32 + rt*16 + quad*4 + r] = sumacc[rt][r];
        }
    }
    __syncthreads();
    if (kw == 0){
        #pragma unroll
        for (int rt = 0; rt < 2; ++rt){
            float inv[4];
            #pragma unroll
            for (int r = 0; r < 4; ++r)
                inv[r] = 1.0f / (sumacc[rt][r] + fps[rw*32 + rt*16 + quad*4 + r]);
            #pragma unroll
            for (int ct = 0; ct < 8; ++ct)
                #pragma unroll
                for (int r = 0; r < 4; ++r){
                    float o = oacc[rt][ct][r]
                            + fpo[(rw*32 + rt*16 + quad*4 + r)*132 + ct*16 + l16];
                    Hm[(rw*32 + rt*16 + quad*4 + r)*136 + ct*16 + l16] = f2bf(o * inv[r]);
                }
        }
    }
    __syncthreads();

    // out GEMM: wave w -> oc [w*64, w*64+64); K = HID = 128
    int mb = mt * 64;
    int oc0 = wave * 64;
    f4 acc2[4][4];
    #pragma unroll
    for (int ot = 0; ot < 4; ++ot)
        #pragma unroll
        for (int nt = 0; nt < 4; ++nt) acc2[ot][nt] = f4{0,0,0,0};
    #pragma unroll
    for (int kk = 0; kk < 4; ++kk){
        bf8 bh[4];
        #pragma unroll
        for (int nt = 0; nt < 4; ++nt)
            bh[nt] = *reinterpret_cast<const bf8*>(&Hm[(nt*16 + l16)*136 + kk*32 + quad*8]);
        #pragma unroll
        for (int ot = 0; ot < 4; ++ot){
            bf8 a = *reinterpret_cast<const bf8*>(&Wf[(oc0 + ot*16 + l16)*HID + kk*32 + quad*8]);
            #pragma unroll
            for (int nt = 0; nt < 4; ++nt)
                acc2[ot][nt] = MFMA(a, bh[nt], acc2[ot][nt]);
        }
    }
    #pragma unroll
    for (int ot = 0; ot < 4; ++ot)
        #pragma unroll
        for (int nt = 0; nt < 4; ++nt){
            int m = mb + nt*16 + l16;
            #pragma unroll
            for (int r = 0; r < 4; ++r){
                int oc = oc0 + ot*16 + quad*4 + r;
                O[(size_t)oc*N_ + m] = acc2[ot][nt][r] + bias[oc] + X[(size_t)oc*N_ + m];
            }
        }
}

// ---------------------------------------------------------------------------
extern "C" void kernel_launch(void* const* d_in, const int* in_sizes, int n_in,
                              void* d_out, int out_size, void* d_ws, size_t ws_size,
                              hipStream_t stream){
    const float* x0  = (const float*)d_in[0];
    const float* x1  = (const float*)d_in[1];
    const float* ew0 = (const float*)d_in[2];
    const float* eb0 = (const float*)d_in[3];
    const float* ew1 = (const float*)d_in[4];
    const float* eb1 = (const float*)d_in[5];
    const float* ow0 = (const float*)d_in[6];
    const float* ob0 = (const float*)d_in[7];
    const float* ow1 = (const float*)d_in[8];
    const float* ob1 = (const float*)d_in[9];

    u16* ws = (u16*)d_ws;
    const size_t QT_E = (size_t)16 * N_ * HID;
    u16* Qt   = ws;
    u16* Kc   = Qt + QT_E;
    u16* Vc   = Kc + QT_E;
    u16* Wbf  = Vc + QT_E;
    u16* weff = Wbf + (size_t)2 * O3 * C_;
    u16* Xt   = (u16*)d_out;                  // scratch phase

    k_wcvt     <<<dim3(96, 2),     dim3(256), 0, stream>>>(ew0, ew1, Wbf);
    k_weff     <<<dim3(256),       dim3(256), 0, stream>>>(ow0, ow1, weff);
    k_transpose<<<dim3(36, 4, 16), dim3(256), 0, stream>>>(x0, x1, Xt);
    k_embed    <<<dim3(36, 6, 16), dim3(256), 0, stream>>>(Xt, Wbf, eb0, eb1, Qt, Kc, Vc);
    k_attn_out <<<dim3(576),       dim3(256), 0, stream>>>(Qt, Kc, Vc, weff, ob0, ob1,
                                                           x0, x1, (float*)d_out);
}

// Round 2
// 271.710 us; speedup vs baseline: 1.1303x; 1.1303x over previous
//
#include <hip/hip_runtime.h>
#include <stdint.h>

// Problem constants
#define B_   8
#define C_   256
#define N_   2304          // 48*48 spatial
#define HID  128
#define O3   384           // 3*HID
#define NH   4
#define SCALE 0.0625f      // 256^-0.5
#define QPRE 0.09016844f   // SCALE * log2(e): q pre-scale so p = exp2(q.k)

typedef unsigned short u16;
typedef short  bf8  __attribute__((ext_vector_type(8)));   // 8 bf16 (4 VGPRs) MFMA A/B frag
typedef float  f4   __attribute__((ext_vector_type(4)));   // MFMA C/D frag
typedef u16    u16x8 __attribute__((ext_vector_type(8)));

#define MFMA(a,b,c) __builtin_amdgcn_mfma_f32_16x16x32_bf16((a),(b),(c),0,0,0)

static __device__ __forceinline__ u16 f2bf(float f){
    union { float f; unsigned int i; } v; v.f = f;
    unsigned int r = v.i + 0x7FFFu + ((v.i >> 16) & 1u);   // round-to-nearest-even
    return (u16)(r >> 16);
}
static __device__ __forceinline__ float fexp2(float x){
#if __has_builtin(__builtin_amdgcn_exp2f)
    return __builtin_amdgcn_exp2f(x);
#else
    return __expf(x * 0.69314718f);
#endif
}
static __device__ __forceinline__ u16 hi16(float f){       // truncating f32->bf16
    union { float f; unsigned int i; } v; v.f = f;
    return (u16)(v.i >> 16);
}
// async global->LDS DMA, 16B per lane; both sides contiguous per lane.
static __device__ __forceinline__ void dma16(const void* g, void* l){
    __builtin_amdgcn_global_load_lds(
        (const __attribute__((address_space(1))) void*)g,
        (__attribute__((address_space(3))) void*)l, 16, 0, 0);
}

// ---------------------------------------------------------------------------
// K0a: convert embed weights fp32 -> bf16.
__global__ __launch_bounds__(256) void k_wcvt(const float* __restrict__ w0,
                                              const float* __restrict__ w1,
                                              u16* __restrict__ Wbf){
    int s = blockIdx.y;
    const float* w = s ? w1 : w0;
    u16* o = Wbf + (size_t)s * (O3 * C_);
    int idx = (blockIdx.x * 256 + threadIdx.x) * 4;
    float4 v = *reinterpret_cast<const float4*>(&w[idx]);
    o[idx+0] = f2bf(v.x); o[idx+1] = f2bf(v.y);
    o[idx+2] = f2bf(v.z); o[idx+3] = f2bf(v.w);
}

// K0b: w_eff^T[s][oc][hc] = sum_head out_w_s[head*HID+hc][oc]  (heads identical)
__global__ __launch_bounds__(256) void k_weff(const float* __restrict__ w0,
                                              const float* __restrict__ w1,
                                              u16* __restrict__ weff){
    int gid = blockIdx.x * 256 + threadIdx.x;   // 2*128*256 = 65536
    int oc = gid & 255, hc = (gid >> 8) & 127, s = gid >> 15;
    const float* w = s ? w1 : w0;
    float acc = 0.f;
    #pragma unroll
    for (int h = 0; h < NH; ++h) acc += w[(h*HID + hc)*C_ + oc];
    weff[(s*C_ + oc)*HID + hc] = f2bf(acc);
}

// ---------------------------------------------------------------------------
// K1a: transpose+convert X[bs][c][n] fp32 -> Xt[bs][n][c] bf16 (Xt in d_out)
__global__ __launch_bounds__(256) void k_transpose(const float* __restrict__ x0,
                                                   const float* __restrict__ x1,
                                                   u16* __restrict__ Xt){
    __shared__ __align__(16) u16 tile[64][72];
    int z = blockIdx.z, b = z >> 1, s = z & 1;
    const float* X = (s ? x1 : x0) + (size_t)b * (C_ * N_);
    u16* out = Xt + (size_t)z * (N_ * C_);
    int n0 = blockIdx.x * 64, c0 = blockIdx.y * 64;
    int t = threadIdx.x;
    int lr = t >> 4, lc = (t & 15) * 4;
    #pragma unroll
    for (int rep = 0; rep < 4; ++rep){
        int c = lr + rep * 16;
        float4 v = *reinterpret_cast<const float4*>(&X[(size_t)(c0 + c) * N_ + n0 + lc]);
        tile[c][lc+0] = f2bf(v.x); tile[c][lc+1] = f2bf(v.y);
        tile[c][lc+2] = f2bf(v.z); tile[c][lc+3] = f2bf(v.w);
    }
    __syncthreads();
    int row = t >> 3, col8 = (t & 7) * 8;
    #pragma unroll
    for (int rep = 0; rep < 2; ++rep){
        int n = row + rep * 32;
        u16x8 v;
        #pragma unroll
        for (int j = 0; j < 8; ++j) v[j] = tile[col8 + j][n];
        *reinterpret_cast<u16x8*>(&out[(size_t)(n0 + n) * C_ + c0 + col8]) = v;
    }
}

// ---------------------------------------------------------------------------
// K1b: embed GEMM.  Q pre-scaled by QPRE.  K/V written in DMA-friendly
// chunk-interleaved layouts:
//   Kc[z][nc][cc][n&63][8] : elem (n,h) at ((n>>6)*16 + (h>>3))*512 + (n&63)*8 + (h&7)
//   Vc[z][nc][pc][hc][8]   : elem (hc,n) at ((n>>6)*8 + ((n>>3)&7))*1024 + hc*8 + (n&7)
__global__ __launch_bounds__(256, 4) void k_embed(const u16* __restrict__ Xt,
        const u16* __restrict__ Wbf,
        const float* __restrict__ b0, const float* __restrict__ b1,
        u16* __restrict__ Qt, u16* __restrict__ Kc, u16* __restrict__ Vc){
    int z = blockIdx.z, s = z & 1;
    const u16* W = Wbf + (size_t)s * (O3 * C_);
    const float* bias = s ? b1 : b0;
    const u16* Xb = Xt + (size_t)z * (N_ * C_);
    int lane = threadIdx.x & 63, wave = threadIdx.x >> 6;
    int l16 = lane & 15, quad = lane >> 4;
    int o0 = blockIdx.y * 64 + wave * 16;
    int n0 = blockIdx.x * 64;
    f4 acc[4] = {f4{0,0,0,0}, f4{0,0,0,0}, f4{0,0,0,0}, f4{0,0,0,0}};
    #pragma unroll
    for (int kk = 0; kk < 8; ++kk){           // K = 256 = 8 * 32
        bf8 a = *reinterpret_cast<const bf8*>(&W[(o0 + l16) * C_ + kk*32 + quad*8]);
        #pragma unroll
        for (int nt = 0; nt < 4; ++nt){
            bf8 bb = *reinterpret_cast<const bf8*>(&Xb[(size_t)(n0 + nt*16 + l16) * C_ + kk*32 + quad*8]);
            acc[nt] = MFMA(a, bb, acc[nt]);
        }
    }
    size_t zq = (size_t)z * (N_ * HID);
    #pragma unroll
    for (int nt = 0; nt < 4; ++nt){
        int n = n0 + nt*16 + l16;
        #pragma unroll
        for (int r = 0; r < 4; ++r){
            int o = o0 + quad*4 + r;
            float e = acc[nt][r] + bias[o];
            if (o < HID){
                Qt[zq + (size_t)n*HID + o] = f2bf(e * QPRE);
            } else if (o < 2*HID){
                int h = o - HID;
                Kc[zq + ((n>>6)*16 + (h>>3))*512 + ((n&63)<<3) + (h&7)] = f2bf(e);
            } else {
                int hc = o - 2*HID;
                Vc[zq + ((n>>6)*8 + ((n>>3)&7))*1024 + (hc<<3) + (n&7)] = f2bf(e);
            }
        }
    }
}

// ---------------------------------------------------------------------------
// K2 (fused): max-free flash attention + output projection + residual.
//   v3: v1's single-buffer / 3-blocks-per-CU / all-576-resident structure
//   (v2's 2-blocks/CU dbuf caused a 64-block grid tail -> +44%), keeping v2's
//   verified wins: waves split 64 rows x 64 keys as 2 row-halves x 2 key-halves
//   (each K/V ds_read_b128 feeds 2 MFMAs -> main-loop LDS reads halved) and
//   P-tile pad 42 (bank conflicts 811K -> 147K).
//   Key-partial O/rowsum reduced across wave pairs in the epilogue: kw1 parks
//   partial O (f32) in the dead K/V LDS region, kw0 folds it into registers,
//   then the H tile reuses bytes [0,17408) after a barrier.
// LDS map (bytes):
//   main loop: [0,16384) K tile | [16384,32768) V tile | [32768,43520) P (4 x 32x42 u16)
//   epilogue : [0,33792) partial O 64x132 f32 | [33792,34048) partial rowsum 64 f32
//              then [0,17408) H tile 64x136 u16 (after fold barrier)
__global__ __launch_bounds__(256, 3) void k_attn_out(const u16* __restrict__ Qt,
        const u16* __restrict__ Kc, const u16* __restrict__ Vc,
        const u16* __restrict__ weff,
        const float* __restrict__ ob0, const float* __restrict__ ob1,
        const float* __restrict__ x0, const float* __restrict__ x1,
        float* __restrict__ out){
    __shared__ __align__(16) u16 lds[21760];           // 43520 B -> 3 blocks/CU
    int bx = blockIdx.x;                      // 576 = 8 XCD * 72
    int xcd = bx & 7, t = bx >> 3;
    int z  = xcd*2 + (t >= 36 ? 1 : 0);       // XCD x serves z in {2x,2x+1}
    int mt = (t >= 36) ? (t - 36) : t;
    int b = z >> 1, s = z & 1;
    const u16* Q = Qt + (size_t)(b*2 + (1 - s)) * (N_ * HID);
    const u16* K = Kc + (size_t)(b*2 + s)       * (N_ * HID);
    const u16* V = Vc + (size_t)(b*2 + s)       * (N_ * HID);
    const u16* Wf   = weff + (size_t)s * (C_ * HID);
    const float* bias = s ? ob1 : ob0;
    const float* X = (s ? x1 : x0) + (size_t)b * (C_ * N_);
    float* O = out + (size_t)s * ((size_t)B_ * C_ * N_) + (size_t)b * (C_ * N_);
    int lane = threadIdx.x & 63, wave = threadIdx.x >> 6;
    int l16 = lane & 15, quad = lane >> 4;
    int rw = wave & 1, kw = wave >> 1;        // row-half, key-half
    int m0 = mt * 64 + rw * 32;

    // Q fragments for this wave's 32 rows: 2 row-tiles x 4 k-slices
    bf8 aq[2][4];
    #pragma unroll
    for (int rt = 0; rt < 2; ++rt)
        #pragma unroll
        for (int kk = 0; kk < 4; ++kk)
            aq[rt][kk] = *reinterpret_cast<const bf8*>(
                &Q[(size_t)(m0 + rt*16 + l16)*HID + kk*32 + quad*8]);

    bf8 ones;
    #pragma unroll
    for (int j = 0; j < 8; ++j) ones[j] = (short)0x3F80;   // bf16 1.0

    f4 oacc[2][8];
    #pragma unroll
    for (int rt = 0; rt < 2; ++rt)
        #pragma unroll
        for (int ct = 0; ct < 8; ++ct) oacc[rt][ct] = f4{0,0,0,0};
    f4 sumacc[2] = {f4{0,0,0,0}, f4{0,0,0,0}};

    u16* kbuf = lds;                           // 16 KB
    u16* vbuf = lds + 8192;                    // 16 KB
    u16* pw   = lds + 16384 + wave * (32*42);  // per-wave P tile
    const char* Kb = (const char*)K;
    const char* Vb = (const char*)V;

    for (int nc = 0; nc < N_/64; ++nc){
        __syncthreads();                      // previous chunk's LDS reads done
        // stage K tile: 16 x 1 KB contiguous bursts
        #pragma unroll
        for (int j = 0; j < 4; ++j){
            int ik = wave*4 + j;
            dma16(Kb + ((size_t)(nc*16 + ik)*512 + lane*8)*2, &kbuf[ik*512]);
        }
        // stage V tile
        #pragma unroll
        for (int j = 0; j < 4; ++j){
            int iv = wave*4 + j;
            dma16(Vb + ((size_t)(nc*8 + (iv>>1))*1024 + (iv&1)*512 + lane*8)*2,
                  &vbuf[iv*512]);
        }
        __syncthreads();                      // drains vmcnt(0): tiles visible
        // QK: this wave's S quarter = rows [m0,m0+32) x keys [kw*32, kw*32+32)
        f4 sacc[2][2] = {{f4{0,0,0,0}, f4{0,0,0,0}}, {f4{0,0,0,0}, f4{0,0,0,0}}};
        __builtin_amdgcn_s_setprio(1);
        #pragma unroll
        for (int kk = 0; kk < 4; ++kk)
            #pragma unroll
            for (int kt = 0; kt < 2; ++kt){
                bf8 bk = *reinterpret_cast<const bf8*>(
                    &kbuf[((kk*4+quad)*64 + kw*32 + kt*16 + l16)*8]);
                sacc[0][kt] = MFMA(aq[0][kk], bk, sacc[0][kt]);   // 1 read -> 2 MFMA
                sacc[1][kt] = MFMA(aq[1][kk], bk, sacc[1][kt]);
            }
        __builtin_amdgcn_s_setprio(0);
        // p = exp2(s), truncating bf16 store to per-wave P tile
        #pragma unroll
        for (int rt = 0; rt < 2; ++rt)
            #pragma unroll
            for (int kt = 0; kt < 2; ++kt)
                #pragma unroll
                for (int r = 0; r < 4; ++r)
                    pw[(rt*16 + quad*4 + r)*42 + kt*16 + l16] = hi16(fexp2(sacc[rt][kt][r]));
        // PV + rowsum over this wave's 32-key half (K-dim = 32 -> single MFMA step)
        bf8 ap[2];
        #pragma unroll
        for (int rt = 0; rt < 2; ++rt)
            ap[rt] = *reinterpret_cast<const bf8*>(&pw[(rt*16 + l16)*42 + quad*8]);
        __builtin_amdgcn_s_setprio(1);
        sumacc[0] = MFMA(ap[0], ones, sumacc[0]);
        sumacc[1] = MFMA(ap[1], ones, sumacc[1]);
        #pragma unroll
        for (int ct = 0; ct < 8; ++ct){
            bf8 bv = *reinterpret_cast<const bf8*>(
                &vbuf[((kw*4+quad)*128 + ct*16 + l16)*8]);
            oacc[0][ct] = MFMA(ap[0], bv, oacc[0][ct]);           // 1 read -> 2 MFMA
            oacc[1][ct] = MFMA(ap[1], bv, oacc[1][ct]);
        }
        __builtin_amdgcn_s_setprio(0);
    }

    // ---- epilogue: reduce key-halves, normalize, out-GEMM -------------------
    __syncthreads();                           // all K/V/P LDS traffic done
    float* fpo = (float*)lds;                  // 64 x 132 f32 partial O
    float* fps = (float*)((char*)lds + 33792); // 64 f32 partial rowsum
    u16*  Hm   = lds;                          // 64 x 136 u16 H tile (after fold)
    if (kw == 1){
        #pragma unroll
        for (int rt = 0; rt < 2; ++rt){
            #pragma unroll
            for (int ct = 0; ct < 8; ++ct)
                #pragma unroll
                for (int r = 0; r < 4; ++r)
                    fpo[(rw*32 + rt*16 + quad*4 + r)*132 + ct*16 + l16] = oacc[rt][ct][r];
            if (l16 == 0)
                #pragma unroll
                for (int r = 0; r < 4; ++r)
                    fps[rw*32 + rt*16 + quad*4 + r] = sumacc[rt][r];
        }
    }
    __syncthreads();
    float inv[2][4];
    if (kw == 0){
        // fold kw1's partials into registers (no LDS writes yet)
        #pragma unroll
        for (int rt = 0; rt < 2; ++rt){
            #pragma unroll
            for (int r = 0; r < 4; ++r)
                inv[rt][r] = 1.0f / (sumacc[rt][r] + fps[rw*32 + rt*16 + quad*4 + r]);
            #pragma unroll
            for (int ct = 0; ct < 8; ++ct)
                #pragma unroll
                for (int r = 0; r < 4; ++r)
                    oacc[rt][ct][r] += fpo[(rw*32 + rt*16 + quad*4 + r)*132 + ct*16 + l16];
        }
    }
    __syncthreads();                           // all fpo reads complete
    if (kw == 0){
        #pragma unroll
        for (int rt = 0; rt < 2; ++rt)
            #pragma unroll
            for (int ct = 0; ct < 8; ++ct)
                #pragma unroll
                for (int r = 0; r < 4; ++r)
                    Hm[(rw*32 + rt*16 + quad*4 + r)*136 + ct*16 + l16]
                        = f2bf(oacc[rt][ct][r] * inv[rt][r]);
    }
    __syncthreads();

    // out GEMM: wave w -> oc [w*64, w*64+64); K = HID = 128
    int mb = mt * 64;
    int oc0 = wave * 64;
    f4 acc2[4][4];
    #pragma unroll
    for (int ot = 0; ot < 4; ++ot)
        #pragma unroll
        for (int nt = 0; nt < 4; ++nt) acc2[ot][nt] = f4{0,0,0,0};
    #pragma unroll
    for (int kk = 0; kk < 4; ++kk){
        bf8 bh[4];
        #pragma unroll
        for (int nt = 0; nt < 4; ++nt)
            bh[nt] = *reinterpret_cast<const bf8*>(&Hm[(nt*16 + l16)*136 + kk*32 + quad*8]);
        #pragma unroll
        for (int ot = 0; ot < 4; ++ot){
            bf8 a = *reinterpret_cast<const bf8*>(&Wf[(oc0 + ot*16 + l16)*HID + kk*32 + quad*8]);
            #pragma unroll
            for (int nt = 0; nt < 4; ++nt)
                acc2[ot][nt] = MFMA(a, bh[nt], acc2[ot][nt]);
        }
    }
    #pragma unroll
    for (int ot = 0; ot < 4; ++ot)
        #pragma unroll
        for (int nt = 0; nt < 4; ++nt){
            int m = mb + nt*16 + l16;
            #pragma unroll
            for (int r = 0; r < 4; ++r){
                int oc = oc0 + ot*16 + quad*4 + r;
                O[(size_t)oc*N_ + m] = acc2[ot][nt][r] + bias[oc] + X[(size_t)oc*N_ + m];
            }
        }
}

// ---------------------------------------------------------------------------
extern "C" void kernel_launch(void* const* d_in, const int* in_sizes, int n_in,
                              void* d_out, int out_size, void* d_ws, size_t ws_size,
                              hipStream_t stream){
    const float* x0  = (const float*)d_in[0];
    const float* x1  = (const float*)d_in[1];
    const float* ew0 = (const float*)d_in[2];
    const float* eb0 = (const float*)d_in[3];
    const float* ew1 = (const float*)d_in[4];
    const float* eb1 = (const float*)d_in[5];
    const float* ow0 = (const float*)d_in[6];
    const float* ob0 = (const float*)d_in[7];
    const float* ow1 = (const float*)d_in[8];
    const float* ob1 = (const float*)d_in[9];

    u16* ws = (u16*)d_ws;
    const size_t QT_E = (size_t)16 * N_ * HID;
    u16* Qt   = ws;
    u16* Kc   = Qt + QT_E;
    u16* Vc   = Kc + QT_E;
    u16* Wbf  = Vc + QT_E;
    u16* weff = Wbf + (size_t)2 * O3 * C_;
    u16* Xt   = (u16*)d_out;                  // scratch phase

    k_wcvt     <<<dim3(96, 2),     dim3(256), 0, stream>>>(ew0, ew1, Wbf);
    k_weff     <<<dim3(256),       dim3(256), 0, stream>>>(ow0, ow1, weff);
    k_transpose<<<dim3(36, 4, 16), dim3(256), 0, stream>>>(x0, x1, Xt);
    k_embed    <<<dim3(36, 6, 16), dim3(256), 0, stream>>>(Xt, Wbf, eb0, eb1, Qt, Kc, Vc);
    k_attn_out <<<dim3(576),       dim3(256), 0, stream>>>(Qt, Kc, Vc, weff, ob0, ob1,
                                                           x0, x1, (float*)d_out);
}